// Round 8
// baseline (263.756 us; speedup 1.0000x reference)
//
#include <hip/hip_runtime.h>
#include <hip/hip_bf16.h>
#include <hip/hip_fp16.h>

#define D 64
#define RB 128            // rows per bin (7-bit local row)
#define NB_MAX 1024       // max bins (n_nodes <= 2^17)
#define NBLK1 512         // chunk blocks (2/CU)
#define P1CAP 6272        // LDS stage capacity (recs) = 50,176 B
#define CAP 5120          // bin-sort LDS capacity (recs) = 40 KB

typedef unsigned long long ull;
typedef unsigned short u16;

// rec = [ val:f32 (hi32) | localrow:bits17-23 | col:bits0-16 ]
__device__ __forceinline__ ull pack_rec(float v, int r, int c) {
    return ((ull)__float_as_uint(v) << 32) |
           (ull)(((unsigned)(r & (RB - 1)) << 17) | (unsigned)c);
}

// ---------------- fallback: atomic kernel (guard path) ----------------
__global__ __launch_bounds__(256) void spmm_atomic_kernel(
    const float* __restrict__ x,
    const int*   __restrict__ edge_row,
    const int*   __restrict__ edge_col,
    const float* __restrict__ edge_val,
    float*       __restrict__ out,
    int n_edges)
{
    const int gtid = blockIdx.x * blockDim.x + threadIdx.x;
    const int wave = gtid >> 6;
    const int lane = threadIdx.x & 63;
    if (wave >= n_edges) return;
    const int   r = edge_row[wave];
    const int   c = edge_col[wave];
    const float v = edge_val[wave];
    atomicAdd(&out[(size_t)r * D + lane], v * x[(size_t)c * D + lane]);
}

// ---------------- KA: per-block row histogram + x->fp16 (fused; independent work) --
// Also resets the done counter consumed by KB (same stream => ordered).
__global__ __launch_bounds__(256) void ka_hist_tohalf_kernel(
    const int* __restrict__ rows, u16* __restrict__ counts,
    const float* __restrict__ x, __half2* __restrict__ xh2,
    int* __restrict__ done,
    int n_edges, int nb, int chunk, int n4)
{
    __shared__ int cnt[NB_MAX];
    const int t = threadIdx.x, blk = blockIdx.x;
    const int e0 = blk * chunk;
    const int e1 = min(e0 + chunk, n_edges);

    if (blk == 0 && t == 0) *done = 0;

    for (int i = t; i < nb; i += 256) cnt[i] = 0;
    __syncthreads();

    for (int i = e0 + t * 4; i < e1; i += 1024) {
        if (i + 4 <= e1) {
            const int4 r4 = *(const int4*)(rows + i);
            atomicAdd(&cnt[r4.x >> 7], 1);
            atomicAdd(&cnt[r4.y >> 7], 1);
            atomicAdd(&cnt[r4.z >> 7], 1);
            atomicAdd(&cnt[r4.w >> 7], 1);
        } else {
            for (int k = i; k < e1; ++k) atomicAdd(&cnt[rows[k] >> 7], 1);
        }
    }
    __syncthreads();
    for (int i = t; i < nb; i += 256)
        counts[(size_t)i * NBLK1 + blk] = (u16)cnt[i];

    // fused tohalf (grid-stride)
    for (int i = blk * 256 + t; i < n4; i += NBLK1 * 256) {
        const float4 v = ((const float4*)x)[i];
        xh2[2 * i + 0] = __floats2half2_rn(v.x, v.y);
        xh2[2 * i + 1] = __floats2half2_rn(v.z, v.w);
    }
}

// ---------------- KB: per-bin block-scan + LAST-BLOCK bin scan (P2+P3 fused) -------
// Decoupled last-block-done pattern (device-scope atomic + threadfence), no
// cooperative launch. Block b scans counts[b][.] -> dest32, binsum[b]; the block
// that brings done to nb performs P3 (binbase scan + flag zeroing) itself.
__global__ __launch_bounds__(256) void kb_scan_kernel(
    const u16* __restrict__ counts, int* __restrict__ dest32,
    int* __restrict__ binsum, int* __restrict__ binbase,
    int* __restrict__ flags, int* __restrict__ done, int nb)
{
    __shared__ int s[256];
    __shared__ int is_last;
    const int b = blockIdx.x, t = threadIdx.x;

    const int la = (int)counts[(size_t)b * NBLK1 + 2 * t];
    const int lb = (int)counts[(size_t)b * NBLK1 + 2 * t + 1];
    const int mysum = la + lb;
    s[t] = mysum;
    for (int off = 1; off < 256; off <<= 1) {
        __syncthreads();
        const int w = (t >= off) ? s[t - off] : 0;
        __syncthreads();
        s[t] += w;
    }
    const int excl = s[t] - mysum;
    dest32[(size_t)b * NBLK1 + 2 * t]     = excl;
    dest32[(size_t)b * NBLK1 + 2 * t + 1] = excl + la;
    if (t == 255) {
        binsum[b] = s[255];
        __threadfence();                         // release binsum/dest32
        is_last = (atomicAdd(done, 1) == nb - 1);
    }
    __syncthreads();

    if (is_last) {
        __threadfence();                         // acquire all binsum
        int pre[4], sum = 0;
        const int base = t * 4;
        #pragma unroll
        for (int k = 0; k < 4; ++k) {
            const int idx = base + k;
            const int v = (idx < nb) ? binsum[idx] : 0;
            pre[k] = sum; sum += v;
        }
        s[t] = sum;
        for (int off = 1; off < 256; off <<= 1) {
            __syncthreads();
            const int w = (t >= off) ? s[t - off] : 0;
            __syncthreads();
            s[t] += w;
        }
        const int texcl = s[t] - sum;
        #pragma unroll
        for (int k = 0; k < 4; ++k) {
            const int idx = base + k;
            if (idx < nb) { binbase[idx] = texcl + pre[k]; flags[idx] = 0; }
        }
        if (t == 255) binbase[nb] = s[255];
    }
}

// ---------------- P1b: LDS counting sort + DIRECT write to final bin slots ---------
// (byte-identical to r6-verified p1b_sortwrite_kernel)
__global__ __launch_bounds__(256) void p1b_sortwrite_kernel(
    const int* __restrict__ rows, const int* __restrict__ cols,
    const float* __restrict__ vals,
    const u16* __restrict__ counts, const int* __restrict__ dest32,
    const int* __restrict__ binbase,
    ull* __restrict__ recs, int n_edges, int nb, int chunk)
{
    __shared__ ull stage[P1CAP];
    __shared__ u16 binof[P1CAP];
    __shared__ int cnt[NB_MAX];
    __shared__ u16 doffL[NB_MAX];
    __shared__ int gbase[NB_MAX];
    __shared__ int s[256];
    const int t = threadIdx.x, blk = blockIdx.x;
    const int e0 = blk * chunk;
    const int e1 = min(e0 + chunk, n_edges);
    const int len = e1 - e0;

    int pre[4], sum = 0, c4[4];
    const int base = t * 4;
    #pragma unroll
    for (int k = 0; k < 4; ++k) {
        const int idx = base + k;
        c4[k] = (idx < nb) ? (int)counts[(size_t)idx * NBLK1 + blk] : 0;
        pre[k] = sum; sum += c4[k];
    }
    s[t] = sum;
    for (int off = 1; off < 256; off <<= 1) {
        __syncthreads();
        const int w = (t >= off) ? s[t - off] : 0;
        __syncthreads();
        s[t] += w;
    }
    const int texcl = s[t] - sum;
    __syncthreads();
    #pragma unroll
    for (int k = 0; k < 4; ++k) {
        const int idx = base + k;
        if (idx < nb) {
            const int e = texcl + pre[k];
            cnt[idx]   = e;
            doffL[idx] = (u16)e;
            gbase[idx] = binbase[idx] + dest32[(size_t)idx * NBLK1 + blk];
        }
    }
    __syncthreads();

    for (int i = e0 + t * 4; i < e1; i += 1024) {
        if (i + 4 <= e1) {
            const int4   r4  = *(const int4*)(rows + i);
            const int4   c4v = *(const int4*)(cols + i);
            const float4 v4  = *(const float4*)(vals + i);
            int p;
            p = atomicAdd(&cnt[r4.x >> 7], 1); stage[p] = pack_rec(v4.x, r4.x, c4v.x); binof[p] = (u16)(r4.x >> 7);
            p = atomicAdd(&cnt[r4.y >> 7], 1); stage[p] = pack_rec(v4.y, r4.y, c4v.y); binof[p] = (u16)(r4.y >> 7);
            p = atomicAdd(&cnt[r4.z >> 7], 1); stage[p] = pack_rec(v4.z, r4.z, c4v.z); binof[p] = (u16)(r4.z >> 7);
            p = atomicAdd(&cnt[r4.w >> 7], 1); stage[p] = pack_rec(v4.w, r4.w, c4v.w); binof[p] = (u16)(r4.w >> 7);
        } else {
            for (int k = i; k < e1; ++k) {
                const int p = atomicAdd(&cnt[rows[k] >> 7], 1);
                stage[p] = pack_rec(vals[k], rows[k], cols[k]);
                binof[p] = (u16)(rows[k] >> 7);
            }
        }
    }
    __syncthreads();

    for (int i = t; i < len; i += 256) {
        const int bin = (int)binof[i];
        recs[gbase[bin] + (i - (int)doffL[bin])] = stage[i];
    }
}

// ---------------- P4': per-bin IN-PLACE key-sort (r6-verified) ---------------------
__global__ __launch_bounds__(256) void p4_sortbin_kernel(
    const int* __restrict__ binbase,
    ull* __restrict__ recs, int* __restrict__ offsets_row, int* __restrict__ flags,
    int n_nodes)
{
    __shared__ ull stage[CAP];
    __shared__ int cnt[1024];
    __shared__ int s[256];
    const int b = blockIdx.x, t = threadIdx.x;
    const int s0  = binbase[b];
    const int len = binbase[b + 1] - s0;

    if (len > CAP) {
        if (t == 0) {
            flags[b] = 1;
            if (b * RB <= n_nodes) offsets_row[b * RB] = s0;
        }
        return;
    }

    for (int i = t; i < 1024; i += 256) cnt[i] = 0;
    __syncthreads();

    for (int i = t; i < len; i += 256) {
        const ull rr = recs[s0 + i];
        stage[i] = rr;
        const int key = ((int)((rr >> 17) & (RB - 1)) << 3) |
                        (int)(((unsigned)rr & 0x1FFFF) >> 14);
        atomicAdd(&cnt[key], 1);
    }
    __syncthreads();

    int v[4], pre[4], sum = 0;
    const int base = t * 4;
    #pragma unroll
    for (int k = 0; k < 4; ++k) { v[k] = cnt[base + k]; pre[k] = sum; sum += v[k]; }
    s[t] = sum;
    for (int off = 1; off < 256; off <<= 1) {
        __syncthreads();
        const int w = (t >= off) ? s[t - off] : 0;
        __syncthreads();
        s[t] += w;
    }
    const int texcl = s[t] - sum;
    __syncthreads();
    #pragma unroll
    for (int k = 0; k < 4; ++k) cnt[base + k] = texcl + pre[k];
    __syncthreads();

    if (t <= RB) {
        const int r = b * RB + t;
        if (r <= n_nodes)
            offsets_row[r] = s0 + ((t == RB) ? len : cnt[t << 3]);
    }
    __syncthreads();

    for (int i = t; i < len; i += 256) {
        const ull rr = stage[i];
        const int key = ((int)((rr >> 17) & (RB - 1)) << 3) |
                        (int)(((unsigned)rr & 0x1FFFF) >> 14);
        const int p = atomicAdd(&cnt[key], 1);
        recs[s0 + p] = rr;
    }
}

// ---------------- K6h2: CSR SpMM, split-wave half2 gathers (r3/r6 verified 84us) ---
__global__ __launch_bounds__(256, 8) void spmm_csr_half2_kernel(
    const __half* __restrict__ xh,
    const int*   __restrict__ offsets_row,
    const int*   __restrict__ binbase,
    const ull*   __restrict__ recs,
    const int*   __restrict__ flags,
    float*       __restrict__ out,
    int n_nodes)
{
    const int row  = blockIdx.x * 4 + (threadIdx.x >> 6);
    if (row >= n_nodes) return;
    const int lane = threadIdx.x & 63;
    const int b    = row >> 7;

    if (__builtin_expect(flags[b], 0)) {
        float acc = 0.f;
        const int s  = binbase[b];
        const int e  = binbase[b + 1];
        const int lr = row & (RB - 1);
        for (int j = s; j < e; ++j) {
            const ull rec = recs[j];
            if ((int)((rec >> 17) & (RB - 1)) == lr) {
                const int   c = (int)((unsigned)rec & 0x1FFFF);
                const float v = __uint_as_float((unsigned)(rec >> 32));
                acc += v * __half2float(xh[(size_t)c * D + lane]);
            }
        }
        out[(size_t)row * D + lane] = acc;
        return;
    }

    const __half2* xh2 = (const __half2*)xh;
    const int half = lane >> 5;
    const int fl   = lane & 31;

    const int s = offsets_row[row];
    const int e = offsets_row[row + 1];
    float accx = 0.f, accy = 0.f;

    int j = s;
    for (; j + 16 <= e; j += 16) {
        float vv[8]; int aa[8];
        #pragma unroll
        for (int k = 0; k < 8; ++k) {
            const ull rec = recs[j + 2 * k + half];
            vv[k] = __uint_as_float((unsigned)(rec >> 32));
            aa[k] = ((int)((unsigned)rec & 0x1FFFF) << 5) + fl;
        }
        __half2 hv[8];
        #pragma unroll
        for (int k = 0; k < 8; ++k) hv[k] = xh2[aa[k]];
        __builtin_amdgcn_sched_barrier(0);
        #pragma unroll
        for (int k = 0; k < 8; ++k) {
            const float2 xf = __half22float2(hv[k]);
            accx = fmaf(vv[k], xf.x, accx);
            accy = fmaf(vv[k], xf.y, accy);
        }
    }
    if (j < e) {
        const int safe = e - 1;
        float vv[8]; int aa[8];
        #pragma unroll
        for (int k = 0; k < 8; ++k) {
            const int  idx = j + 2 * k + half;
            const bool ok  = idx < e;
            const ull  rec = recs[ok ? idx : safe];
            vv[k] = ok ? __uint_as_float((unsigned)(rec >> 32)) : 0.f;
            aa[k] = ((int)((unsigned)rec & 0x1FFFF) << 5) + fl;
        }
        __half2 hv[8];
        #pragma unroll
        for (int k = 0; k < 8; ++k) hv[k] = xh2[aa[k]];
        __builtin_amdgcn_sched_barrier(0);
        #pragma unroll
        for (int k = 0; k < 8; ++k) {
            const float2 xf = __half22float2(hv[k]);
            accx = fmaf(vv[k], xf.x, accx);
            accy = fmaf(vv[k], xf.y, accy);
        }
    }

    accx += __shfl_xor(accx, 32);
    accy += __shfl_xor(accy, 32);
    if (half == 0) {
        float2 o; o.x = accx; o.y = accy;
        ((float2*)out)[(size_t)row * 32 + fl] = o;
    }
}

static inline size_t align16(size_t v) { return (v + 15) & ~(size_t)15; }

extern "C" void kernel_launch(void* const* d_in, const int* in_sizes, int n_in,
                              void* d_out, int out_size, void* d_ws, size_t ws_size,
                              hipStream_t stream)
{
    // setup_inputs order: t, x, edge_row, edge_col, edge_val
    const float* x        = (const float*)d_in[1];
    const int*   edge_row = (const int*)d_in[2];
    const int*   edge_col = (const int*)d_in[3];
    const float* edge_val = (const float*)d_in[4];
    float*       out      = (float*)d_out;

    const int n_edges = in_sizes[2];
    const int n_nodes = out_size / D;
    const int nb      = (n_nodes + RB - 1) / RB;
    const int chunk   = (((n_edges + NBLK1 - 1) / NBLK1) + 3) & ~3;  // x4 for int4

    // workspace carve
    const size_t off_recs    = 0;                                               // n_edges*8
    const size_t off_xh      = align16(off_recs + (size_t)n_edges * 8);         // n_nodes*128
    const size_t off_counts  = align16(off_xh + (size_t)n_nodes * D * 2);       // nb*NBLK1 u16
    const size_t off_dest    = align16(off_counts + (size_t)nb * NBLK1 * 2);    // nb*NBLK1 int
    const size_t off_binsum  = align16(off_dest + (size_t)nb * NBLK1 * 4);      // nb ints
    const size_t off_binbase = align16(off_binsum + (size_t)nb * 4);            // nb+1 ints
    const size_t off_rowoffs = align16(off_binbase + (size_t)(nb + 1) * 4);     // n_nodes+1 ints
    const size_t off_flags   = align16(off_rowoffs + (size_t)(n_nodes + 1) * 4);// nb ints
    const size_t off_done    = align16(off_flags + (size_t)nb * 4);             // 1 int
    const size_t ws_needed   = off_done + 16;

    if (ws_size < ws_needed || nb > NB_MAX || n_nodes > (1 << 17) ||
        chunk > P1CAP || n_edges < 1) {
        hipMemsetAsync(out, 0, (size_t)out_size * sizeof(float), stream);
        const int n_blocks = (n_edges + 3) / 4;
        spmm_atomic_kernel<<<n_blocks, 256, 0, stream>>>(
            x, edge_row, edge_col, edge_val, out, n_edges);
        return;
    }

    char* ws = (char*)d_ws;
    ull*     recs        = (ull*)(ws + off_recs);
    __half*  xh          = (__half*)(ws + off_xh);
    __half2* xh2         = (__half2*)xh;
    u16*     counts      = (u16*)(ws + off_counts);
    int*     dest32      = (int*)(ws + off_dest);
    int*     binsum      = (int*)(ws + off_binsum);
    int*     binbase     = (int*)(ws + off_binbase);
    int*     offsets_row = (int*)(ws + off_rowoffs);
    int*     flags       = (int*)(ws + off_flags);
    int*     done        = (int*)(ws + off_done);

    const int n4 = (n_nodes * D) / 4;

    // KA: hist + tohalf (fused) + done reset
    ka_hist_tohalf_kernel<<<NBLK1, 256, 0, stream>>>(
        edge_row, counts, x, xh2, done, n_edges, nb, chunk, n4);
    // KB: per-bin block scan + last-block bin scan (P2+P3 fused, no coop launch)
    kb_scan_kernel<<<nb, 256, 0, stream>>>(
        counts, dest32, binsum, binbase, flags, done, nb);
    // P1b: LDS counting sort + direct write to final bin regions
    p1b_sortwrite_kernel<<<NBLK1, 256, 0, stream>>>(
        edge_row, edge_col, edge_val, counts, dest32, binbase,
        recs, n_edges, nb, chunk);
    // P4': per-bin in-place sort + row offsets
    p4_sortbin_kernel<<<nb, 256, 0, stream>>>(
        binbase, recs, offsets_row, flags, n_nodes);
    // K6h2: CSR SpMM (r3/r6 verified)
    spmm_csr_half2_kernel<<<(n_nodes + 3) / 4, 256, 0, stream>>>(
        xh, offsets_row, binbase, recs, flags, out, n_nodes);
}

// Round 9
// 258.762 us; speedup vs baseline: 1.0193x; 1.0193x over previous
//
#include <hip/hip_runtime.h>
#include <hip/hip_bf16.h>
#include <hip/hip_fp16.h>

#define D 64
#define RB 128            // rows per bin (7-bit local row)
#define NB_MAX 1024       // max bins (n_nodes <= 2^17)
#define NBLK1 512         // chunk blocks (2/CU)
#define P1CAP 6272        // LDS stage capacity (recs) = 50,176 B
#define CAP 5120          // bin-sort LDS capacity (recs) = 40 KB

typedef unsigned long long ull;
typedef unsigned short u16;

// rec = [ val:f32 (hi32) | localrow:bits17-23 | col:bits0-16 ]
__device__ __forceinline__ ull pack_rec(float v, int r, int c) {
    return ((ull)__float_as_uint(v) << 32) |
           (ull)(((unsigned)(r & (RB - 1)) << 17) | (unsigned)c);
}

// ---------------- fallback: atomic kernel (guard path) ----------------
__global__ __launch_bounds__(256) void spmm_atomic_kernel(
    const float* __restrict__ x,
    const int*   __restrict__ edge_row,
    const int*   __restrict__ edge_col,
    const float* __restrict__ edge_val,
    float*       __restrict__ out,
    int n_edges)
{
    const int gtid = blockIdx.x * blockDim.x + threadIdx.x;
    const int wave = gtid >> 6;
    const int lane = threadIdx.x & 63;
    if (wave >= n_edges) return;
    const int   r = edge_row[wave];
    const int   c = edge_col[wave];
    const float v = edge_val[wave];
    atomicAdd(&out[(size_t)r * D + lane], v * x[(size_t)c * D + lane]);
}

// ---------------- P1a: per-block row histogram -> counts[bin][blk] (r6-verified) ---
__global__ __launch_bounds__(256) void p1a_hist_kernel(
    const int* __restrict__ rows, u16* __restrict__ counts,
    int n_edges, int nb, int chunk)
{
    __shared__ int cnt[NB_MAX];
    const int t = threadIdx.x, blk = blockIdx.x;
    const int e0 = blk * chunk;
    const int e1 = min(e0 + chunk, n_edges);

    for (int i = t; i < nb; i += 256) cnt[i] = 0;
    __syncthreads();
    for (int i = e0 + t * 4; i < e1; i += 1024) {
        if (i + 4 <= e1) {
            const int4 r4 = *(const int4*)(rows + i);
            atomicAdd(&cnt[r4.x >> 7], 1);
            atomicAdd(&cnt[r4.y >> 7], 1);
            atomicAdd(&cnt[r4.z >> 7], 1);
            atomicAdd(&cnt[r4.w >> 7], 1);
        } else {
            for (int k = i; k < e1; ++k) atomicAdd(&cnt[rows[k] >> 7], 1);
        }
    }
    __syncthreads();
    for (int i = t; i < nb; i += 256)
        counts[(size_t)i * NBLK1 + blk] = (u16)cnt[i];
}

// ---------------- P2': per-bin exclusive scan over 512 blocks (r6-verified) --------
__global__ __launch_bounds__(256) void p2_scanblocks_kernel(
    const u16* __restrict__ counts, int* __restrict__ dest32,
    int* __restrict__ binsum, int nb)
{
    __shared__ int s[256];
    const int b = blockIdx.x, t = threadIdx.x;
    const int la = (int)counts[(size_t)b * NBLK1 + 2 * t];
    const int lb = (int)counts[(size_t)b * NBLK1 + 2 * t + 1];
    const int mysum = la + lb;
    s[t] = mysum;
    for (int off = 1; off < 256; off <<= 1) {
        __syncthreads();
        const int w = (t >= off) ? s[t - off] : 0;
        __syncthreads();
        s[t] += w;
    }
    const int excl = s[t] - mysum;
    dest32[(size_t)b * NBLK1 + 2 * t]     = excl;
    dest32[(size_t)b * NBLK1 + 2 * t + 1] = excl + la;
    if (t == 255) binsum[b] = s[255];
}

// ---------------- P3: exclusive scan over bins (r6-verified) -----------------------
__global__ __launch_bounds__(1024) void p3_scanbins_kernel(
    const int* __restrict__ binsum, int* __restrict__ binbase,
    int* __restrict__ flags, int nb)
{
    __shared__ int s[1024];
    const int t = threadIdx.x;
    const int mine = (t < nb) ? binsum[t] : 0;
    s[t] = mine;
    for (int off = 1; off < 1024; off <<= 1) {
        __syncthreads();
        const int v = (t >= off) ? s[t - off] : 0;
        __syncthreads();
        s[t] += v;
    }
    if (t < nb) { binbase[t] = s[t] - mine; flags[t] = 0; }
    if (t == nb - 1) binbase[nb] = s[t];
}

// ---------------- P1b: LDS counting sort + direct write to final bins (r6) ---------
__global__ __launch_bounds__(256) void p1b_sortwrite_kernel(
    const int* __restrict__ rows, const int* __restrict__ cols,
    const float* __restrict__ vals,
    const u16* __restrict__ counts, const int* __restrict__ dest32,
    const int* __restrict__ binbase,
    ull* __restrict__ recs, int n_edges, int nb, int chunk)
{
    __shared__ ull stage[P1CAP];
    __shared__ u16 binof[P1CAP];
    __shared__ int cnt[NB_MAX];
    __shared__ u16 doffL[NB_MAX];
    __shared__ int gbase[NB_MAX];
    __shared__ int s[256];
    const int t = threadIdx.x, blk = blockIdx.x;
    const int e0 = blk * chunk;
    const int e1 = min(e0 + chunk, n_edges);
    const int len = e1 - e0;

    int pre[4], sum = 0, c4[4];
    const int base = t * 4;
    #pragma unroll
    for (int k = 0; k < 4; ++k) {
        const int idx = base + k;
        c4[k] = (idx < nb) ? (int)counts[(size_t)idx * NBLK1 + blk] : 0;
        pre[k] = sum; sum += c4[k];
    }
    s[t] = sum;
    for (int off = 1; off < 256; off <<= 1) {
        __syncthreads();
        const int w = (t >= off) ? s[t - off] : 0;
        __syncthreads();
        s[t] += w;
    }
    const int texcl = s[t] - sum;
    __syncthreads();
    #pragma unroll
    for (int k = 0; k < 4; ++k) {
        const int idx = base + k;
        if (idx < nb) {
            const int e = texcl + pre[k];
            cnt[idx]   = e;
            doffL[idx] = (u16)e;
            gbase[idx] = binbase[idx] + dest32[(size_t)idx * NBLK1 + blk];
        }
    }
    __syncthreads();

    for (int i = e0 + t * 4; i < e1; i += 1024) {
        if (i + 4 <= e1) {
            const int4   r4  = *(const int4*)(rows + i);
            const int4   c4v = *(const int4*)(cols + i);
            const float4 v4  = *(const float4*)(vals + i);
            int p;
            p = atomicAdd(&cnt[r4.x >> 7], 1); stage[p] = pack_rec(v4.x, r4.x, c4v.x); binof[p] = (u16)(r4.x >> 7);
            p = atomicAdd(&cnt[r4.y >> 7], 1); stage[p] = pack_rec(v4.y, r4.y, c4v.y); binof[p] = (u16)(r4.y >> 7);
            p = atomicAdd(&cnt[r4.z >> 7], 1); stage[p] = pack_rec(v4.z, r4.z, c4v.z); binof[p] = (u16)(r4.z >> 7);
            p = atomicAdd(&cnt[r4.w >> 7], 1); stage[p] = pack_rec(v4.w, r4.w, c4v.w); binof[p] = (u16)(r4.w >> 7);
        } else {
            for (int k = i; k < e1; ++k) {
                const int p = atomicAdd(&cnt[rows[k] >> 7], 1);
                stage[p] = pack_rec(vals[k], rows[k], cols[k]);
                binof[p] = (u16)(rows[k] >> 7);
            }
        }
    }
    __syncthreads();

    for (int i = t; i < len; i += 256) {
        const int bin = (int)binof[i];
        recs[gbase[bin] + (i - (int)doffL[bin])] = stage[i];
    }
}

// ---------------- P4': per-bin in-place key-sort (r6-verified) ---------------------
__global__ __launch_bounds__(256) void p4_sortbin_kernel(
    const int* __restrict__ binbase,
    ull* __restrict__ recs, int* __restrict__ offsets_row, int* __restrict__ flags,
    int n_nodes)
{
    __shared__ ull stage[CAP];
    __shared__ int cnt[1024];
    __shared__ int s[256];
    const int b = blockIdx.x, t = threadIdx.x;
    const int s0  = binbase[b];
    const int len = binbase[b + 1] - s0;

    if (len > CAP) {
        if (t == 0) {
            flags[b] = 1;
            if (b * RB <= n_nodes) offsets_row[b * RB] = s0;
        }
        return;
    }

    for (int i = t; i < 1024; i += 256) cnt[i] = 0;
    __syncthreads();

    for (int i = t; i < len; i += 256) {
        const ull rr = recs[s0 + i];
        stage[i] = rr;
        const int key = ((int)((rr >> 17) & (RB - 1)) << 3) |
                        (int)(((unsigned)rr & 0x1FFFF) >> 14);
        atomicAdd(&cnt[key], 1);
    }
    __syncthreads();

    int v[4], pre[4], sum = 0;
    const int base = t * 4;
    #pragma unroll
    for (int k = 0; k < 4; ++k) { v[k] = cnt[base + k]; pre[k] = sum; sum += v[k]; }
    s[t] = sum;
    for (int off = 1; off < 256; off <<= 1) {
        __syncthreads();
        const int w = (t >= off) ? s[t - off] : 0;
        __syncthreads();
        s[t] += w;
    }
    const int texcl = s[t] - sum;
    __syncthreads();
    #pragma unroll
    for (int k = 0; k < 4; ++k) cnt[base + k] = texcl + pre[k];
    __syncthreads();

    if (t <= RB) {
        const int r = b * RB + t;
        if (r <= n_nodes)
            offsets_row[r] = s0 + ((t == RB) ? len : cnt[t << 3]);
    }
    __syncthreads();

    for (int i = t; i < len; i += 256) {
        const ull rr = stage[i];
        const int key = ((int)((rr >> 17) & (RB - 1)) << 3) |
                        (int)(((unsigned)rr & 0x1FFFF) >> 14);
        const int p = atomicAdd(&cnt[key], 1);
        recs[s0 + p] = rr;
    }
}

// ---------------- P0: x -> fp16 (r6-verified) --------------------------------------
__global__ void tohalf_kernel(const float* __restrict__ x,
                              __half2* __restrict__ xh2, int n4)
{
    for (int i = blockIdx.x * blockDim.x + threadIdx.x; i < n4;
         i += gridDim.x * blockDim.x) {
        const float4 v = ((const float4*)x)[i];
        xh2[2 * i + 0] = __floats2half2_rn(v.x, v.y);
        xh2[2 * i + 1] = __floats2half2_rn(v.z, v.w);
    }
}

// ---------------- K6h2: CSR SpMM, split-wave half2 (r3/r6 verified), row-ranged ----
// Split into 3 row-range launches (~28us each) so the LARGEST preprocessing kernel
// surfaces in rocprof's top-5 with its counters (top-5 = 5 iterations of the
// biggest dispatch; K6 at 84us has masked all pre-kernels for 8 rounds).
__global__ __launch_bounds__(256, 8) void spmm_csr_half2_kernel(
    const __half* __restrict__ xh,
    const int*   __restrict__ offsets_row,
    const int*   __restrict__ binbase,
    const ull*   __restrict__ recs,
    const int*   __restrict__ flags,
    float*       __restrict__ out,
    int row_base, int row_end)
{
    const int row  = row_base + blockIdx.x * 4 + (threadIdx.x >> 6);
    if (row >= row_end) return;
    const int lane = threadIdx.x & 63;
    const int b    = row >> 7;

    if (__builtin_expect(flags[b], 0)) {
        float acc = 0.f;
        const int s  = binbase[b];
        const int e  = binbase[b + 1];
        const int lr = row & (RB - 1);
        for (int j = s; j < e; ++j) {
            const ull rec = recs[j];
            if ((int)((rec >> 17) & (RB - 1)) == lr) {
                const int   c = (int)((unsigned)rec & 0x1FFFF);
                const float v = __uint_as_float((unsigned)(rec >> 32));
                acc += v * __half2float(xh[(size_t)c * D + lane]);
            }
        }
        out[(size_t)row * D + lane] = acc;
        return;
    }

    const __half2* xh2 = (const __half2*)xh;
    const int half = lane >> 5;
    const int fl   = lane & 31;

    const int s = offsets_row[row];
    const int e = offsets_row[row + 1];
    float accx = 0.f, accy = 0.f;

    int j = s;
    for (; j + 16 <= e; j += 16) {
        float vv[8]; int aa[8];
        #pragma unroll
        for (int k = 0; k < 8; ++k) {
            const ull rec = recs[j + 2 * k + half];
            vv[k] = __uint_as_float((unsigned)(rec >> 32));
            aa[k] = ((int)((unsigned)rec & 0x1FFFF) << 5) + fl;
        }
        __half2 hv[8];
        #pragma unroll
        for (int k = 0; k < 8; ++k) hv[k] = xh2[aa[k]];
        __builtin_amdgcn_sched_barrier(0);
        #pragma unroll
        for (int k = 0; k < 8; ++k) {
            const float2 xf = __half22float2(hv[k]);
            accx = fmaf(vv[k], xf.x, accx);
            accy = fmaf(vv[k], xf.y, accy);
        }
    }
    if (j < e) {
        const int safe = e - 1;
        float vv[8]; int aa[8];
        #pragma unroll
        for (int k = 0; k < 8; ++k) {
            const int  idx = j + 2 * k + half;
            const bool ok  = idx < e;
            const ull  rec = recs[ok ? idx : safe];
            vv[k] = ok ? __uint_as_float((unsigned)(rec >> 32)) : 0.f;
            aa[k] = ((int)((unsigned)rec & 0x1FFFF) << 5) + fl;
        }
        __half2 hv[8];
        #pragma unroll
        for (int k = 0; k < 8; ++k) hv[k] = xh2[aa[k]];
        __builtin_amdgcn_sched_barrier(0);
        #pragma unroll
        for (int k = 0; k < 8; ++k) {
            const float2 xf = __half22float2(hv[k]);
            accx = fmaf(vv[k], xf.x, accx);
            accy = fmaf(vv[k], xf.y, accy);
        }
    }

    accx += __shfl_xor(accx, 32);
    accy += __shfl_xor(accy, 32);
    if (half == 0) {
        float2 o; o.x = accx; o.y = accy;
        ((float2*)out)[(size_t)row * 32 + fl] = o;
    }
}

static inline size_t align16(size_t v) { return (v + 15) & ~(size_t)15; }

extern "C" void kernel_launch(void* const* d_in, const int* in_sizes, int n_in,
                              void* d_out, int out_size, void* d_ws, size_t ws_size,
                              hipStream_t stream)
{
    // setup_inputs order: t, x, edge_row, edge_col, edge_val
    const float* x        = (const float*)d_in[1];
    const int*   edge_row = (const int*)d_in[2];
    const int*   edge_col = (const int*)d_in[3];
    const float* edge_val = (const float*)d_in[4];
    float*       out      = (float*)d_out;

    const int n_edges = in_sizes[2];
    const int n_nodes = out_size / D;
    const int nb      = (n_nodes + RB - 1) / RB;
    const int chunk   = (((n_edges + NBLK1 - 1) / NBLK1) + 3) & ~3;  // x4 for int4

    // workspace carve
    const size_t off_recs    = 0;                                               // n_edges*8
    const size_t off_xh      = align16(off_recs + (size_t)n_edges * 8);         // n_nodes*128
    const size_t off_counts  = align16(off_xh + (size_t)n_nodes * D * 2);       // nb*NBLK1 u16
    const size_t off_dest    = align16(off_counts + (size_t)nb * NBLK1 * 2);    // nb*NBLK1 int
    const size_t off_binsum  = align16(off_dest + (size_t)nb * NBLK1 * 4);      // nb ints
    const size_t off_binbase = align16(off_binsum + (size_t)nb * 4);            // nb+1 ints
    const size_t off_rowoffs = align16(off_binbase + (size_t)(nb + 1) * 4);     // n_nodes+1 ints
    const size_t off_flags   = align16(off_rowoffs + (size_t)(n_nodes + 1) * 4);// nb ints
    const size_t ws_needed   = off_flags + (size_t)nb * 4;

    if (ws_size < ws_needed || nb > NB_MAX || n_nodes > (1 << 17) ||
        chunk > P1CAP || n_edges < 1) {
        hipMemsetAsync(out, 0, (size_t)out_size * sizeof(float), stream);
        const int n_blocks = (n_edges + 3) / 4;
        spmm_atomic_kernel<<<n_blocks, 256, 0, stream>>>(
            x, edge_row, edge_col, edge_val, out, n_edges);
        return;
    }

    char* ws = (char*)d_ws;
    ull*     recs        = (ull*)(ws + off_recs);
    __half*  xh          = (__half*)(ws + off_xh);
    __half2* xh2         = (__half2*)xh;
    u16*     counts      = (u16*)(ws + off_counts);
    int*     dest32      = (int*)(ws + off_dest);
    int*     binsum      = (int*)(ws + off_binsum);
    int*     binbase     = (int*)(ws + off_binbase);
    int*     offsets_row = (int*)(ws + off_rowoffs);
    int*     flags       = (int*)(ws + off_flags);

    const int n4 = (n_nodes * D) / 4;

    // r6-verified preprocessing pipeline
    p1a_hist_kernel<<<NBLK1, 256, 0, stream>>>(
        edge_row, counts, n_edges, nb, chunk);
    p2_scanblocks_kernel<<<nb, 256, 0, stream>>>(counts, dest32, binsum, nb);
    p3_scanbins_kernel<<<1, 1024, 0, stream>>>(binsum, binbase, flags, nb);
    p1b_sortwrite_kernel<<<NBLK1, 256, 0, stream>>>(
        edge_row, edge_col, edge_val, counts, dest32, binbase,
        recs, n_edges, nb, chunk);
    p4_sortbin_kernel<<<nb, 256, 0, stream>>>(
        binbase, recs, offsets_row, flags, n_nodes);
    tohalf_kernel<<<2048, 256, 0, stream>>>(x, xh2, n4);

    // K6h2 in 3 row-range launches (~28us each) to unmask pre-kernels in top-5
    const int third = (((n_nodes + 2) / 3) + 3) & ~3;   // multiple of 4 rows
    for (int p = 0; p < 3; ++p) {
        const int rb = p * third;
        const int re = min(rb + third, n_nodes);
        if (re > rb) {
            const int grid = (re - rb + 3) / 4;
            spmm_csr_half2_kernel<<<grid, 256, 0, stream>>>(
                xh, offsets_row, binbase, recs, flags, out, rb, re);
        }
    }
}

// Round 10
// 258.223 us; speedup vs baseline: 1.0214x; 1.0021x over previous
//
#include <hip/hip_runtime.h>
#include <hip/hip_bf16.h>
#include <hip/hip_fp16.h>

#define D 64
#define RB 128            // rows per bin (7-bit local row)
#define NB_MAX 1024       // max bins (n_nodes <= 2^17)
#define NBLK1 1024        // chunk blocks (r10: 512->1024 for 2x pre-kernel occupancy)
#define P1CAP 3200        // LDS stage capacity (recs) = 25.6 KB (chunk <= 3200)
#define CAP 5120          // bin-sort LDS capacity (recs) = 40 KB

typedef unsigned long long ull;
typedef unsigned short u16;

// rec = [ val:f32 (hi32) | localrow:bits17-23 | col:bits0-16 ]
__device__ __forceinline__ ull pack_rec(float v, int r, int c) {
    return ((ull)__float_as_uint(v) << 32) |
           (ull)(((unsigned)(r & (RB - 1)) << 17) | (unsigned)c);
}

// ---------------- fallback: atomic kernel (guard path) ----------------
__global__ __launch_bounds__(256) void spmm_atomic_kernel(
    const float* __restrict__ x,
    const int*   __restrict__ edge_row,
    const int*   __restrict__ edge_col,
    const float* __restrict__ edge_val,
    float*       __restrict__ out,
    int n_edges)
{
    const int gtid = blockIdx.x * blockDim.x + threadIdx.x;
    const int wave = gtid >> 6;
    const int lane = threadIdx.x & 63;
    if (wave >= n_edges) return;
    const int   r = edge_row[wave];
    const int   c = edge_col[wave];
    const float v = edge_val[wave];
    atomicAdd(&out[(size_t)r * D + lane], v * x[(size_t)c * D + lane]);
}

// ---------------- P1a: per-block row histogram -> counts[bin][blk] -----------------
// r10: grid 1024 (4 blocks/CU; was grid-limited to 2/CU at 512). LDS only 4KB.
__global__ __launch_bounds__(256) void p1a_hist_kernel(
    const int* __restrict__ rows, u16* __restrict__ counts,
    int n_edges, int nb, int chunk)
{
    __shared__ int cnt[NB_MAX];
    const int t = threadIdx.x, blk = blockIdx.x;
    const int e0 = blk * chunk;
    const int e1 = min(e0 + chunk, n_edges);

    for (int i = t; i < nb; i += 256) cnt[i] = 0;
    __syncthreads();
    for (int i = e0 + t * 4; i < e1; i += 1024) {
        if (i + 4 <= e1) {
            const int4 r4 = *(const int4*)(rows + i);
            atomicAdd(&cnt[r4.x >> 7], 1);
            atomicAdd(&cnt[r4.y >> 7], 1);
            atomicAdd(&cnt[r4.z >> 7], 1);
            atomicAdd(&cnt[r4.w >> 7], 1);
        } else {
            for (int k = i; k < e1; ++k) atomicAdd(&cnt[rows[k] >> 7], 1);
        }
    }
    __syncthreads();
    for (int i = t; i < nb; i += 256)
        counts[(size_t)i * NBLK1 + blk] = (u16)cnt[i];
}

// ---------------- P2': per-bin exclusive scan over 1024 blocks -> dest32, binsum ---
__global__ __launch_bounds__(256) void p2_scanblocks_kernel(
    const u16* __restrict__ counts, int* __restrict__ dest32,
    int* __restrict__ binsum, int nb)
{
    __shared__ int s[256];
    const int b = blockIdx.x, t = threadIdx.x;
    const int base = t * 4;
    int c4[4], pre[4], sum = 0;
    #pragma unroll
    for (int k = 0; k < 4; ++k) {
        c4[k] = (int)counts[(size_t)b * NBLK1 + base + k];
        pre[k] = sum; sum += c4[k];
    }
    s[t] = sum;
    for (int off = 1; off < 256; off <<= 1) {
        __syncthreads();
        const int w = (t >= off) ? s[t - off] : 0;
        __syncthreads();
        s[t] += w;
    }
    const int excl = s[t] - sum;
    #pragma unroll
    for (int k = 0; k < 4; ++k)
        dest32[(size_t)b * NBLK1 + base + k] = excl + pre[k];
    if (t == 255) binsum[b] = s[255];
}

// ---------------- P3: exclusive scan over bins (r6-verified) -----------------------
__global__ __launch_bounds__(1024) void p3_scanbins_kernel(
    const int* __restrict__ binsum, int* __restrict__ binbase,
    int* __restrict__ flags, int nb)
{
    __shared__ int s[1024];
    const int t = threadIdx.x;
    const int mine = (t < nb) ? binsum[t] : 0;
    s[t] = mine;
    for (int off = 1; off < 1024; off <<= 1) {
        __syncthreads();
        const int v = (t >= off) ? s[t - off] : 0;
        __syncthreads();
        s[t] += v;
    }
    if (t < nb) { binbase[t] = s[t] - mine; flags[t] = 0; }
    if (t == nb - 1) binbase[nb] = s[t];
}

// ---------------- P1b: LDS counting sort + direct write to final bins --------------
// r10: LDS 74->41 KB (3 blocks/CU, was 2); gbase-doffL merged into gmd.
__global__ __launch_bounds__(256) void p1b_sortwrite_kernel(
    const int* __restrict__ rows, const int* __restrict__ cols,
    const float* __restrict__ vals,
    const u16* __restrict__ counts, const int* __restrict__ dest32,
    const int* __restrict__ binbase,
    ull* __restrict__ recs, int n_edges, int nb, int chunk)
{
    __shared__ ull stage[P1CAP];    // 25.6 KB
    __shared__ u16 binof[P1CAP];    //  6.4 KB
    __shared__ int cnt[NB_MAX];     //  4.0 KB
    __shared__ int gmd[NB_MAX];     //  4.0 KB (global base minus local start)
    __shared__ int s[256];          //  1.0 KB
    const int t = threadIdx.x, blk = blockIdx.x;
    const int e0 = blk * chunk;
    const int e1 = min(e0 + chunk, n_edges);
    const int len = e1 - e0;

    int pre[4], sum = 0, c4[4];
    const int base = t * 4;
    #pragma unroll
    for (int k = 0; k < 4; ++k) {
        const int idx = base + k;
        c4[k] = (idx < nb) ? (int)counts[(size_t)idx * NBLK1 + blk] : 0;
        pre[k] = sum; sum += c4[k];
    }
    s[t] = sum;
    for (int off = 1; off < 256; off <<= 1) {
        __syncthreads();
        const int w = (t >= off) ? s[t - off] : 0;
        __syncthreads();
        s[t] += w;
    }
    const int texcl = s[t] - sum;
    __syncthreads();
    #pragma unroll
    for (int k = 0; k < 4; ++k) {
        const int idx = base + k;
        if (idx < nb) {
            const int e = texcl + pre[k];                   // local run start
            cnt[idx] = e;                                   // cursor
            gmd[idx] = binbase[idx] + dest32[(size_t)idx * NBLK1 + blk] - e;
        }
    }
    __syncthreads();

    for (int i = e0 + t * 4; i < e1; i += 1024) {
        if (i + 4 <= e1) {
            const int4   r4  = *(const int4*)(rows + i);
            const int4   c4v = *(const int4*)(cols + i);
            const float4 v4  = *(const float4*)(vals + i);
            int p;
            p = atomicAdd(&cnt[r4.x >> 7], 1); stage[p] = pack_rec(v4.x, r4.x, c4v.x); binof[p] = (u16)(r4.x >> 7);
            p = atomicAdd(&cnt[r4.y >> 7], 1); stage[p] = pack_rec(v4.y, r4.y, c4v.y); binof[p] = (u16)(r4.y >> 7);
            p = atomicAdd(&cnt[r4.z >> 7], 1); stage[p] = pack_rec(v4.z, r4.z, c4v.z); binof[p] = (u16)(r4.z >> 7);
            p = atomicAdd(&cnt[r4.w >> 7], 1); stage[p] = pack_rec(v4.w, r4.w, c4v.w); binof[p] = (u16)(r4.w >> 7);
        } else {
            for (int k = i; k < e1; ++k) {
                const int p = atomicAdd(&cnt[rows[k] >> 7], 1);
                stage[p] = pack_rec(vals[k], rows[k], cols[k]);
                binof[p] = (u16)(rows[k] >> 7);
            }
        }
    }
    __syncthreads();

    for (int i = t; i < len; i += 256)
        recs[gmd[(int)binof[i]] + i] = stage[i];
}

// ---------------- P4': per-bin in-place key-sort (r6-verified) ---------------------
__global__ __launch_bounds__(256) void p4_sortbin_kernel(
    const int* __restrict__ binbase,
    ull* __restrict__ recs, int* __restrict__ offsets_row, int* __restrict__ flags,
    int n_nodes)
{
    __shared__ ull stage[CAP];
    __shared__ int cnt[1024];
    __shared__ int s[256];
    const int b = blockIdx.x, t = threadIdx.x;
    const int s0  = binbase[b];
    const int len = binbase[b + 1] - s0;

    if (len > CAP) {
        if (t == 0) {
            flags[b] = 1;
            if (b * RB <= n_nodes) offsets_row[b * RB] = s0;
        }
        return;
    }

    for (int i = t; i < 1024; i += 256) cnt[i] = 0;
    __syncthreads();

    for (int i = t; i < len; i += 256) {
        const ull rr = recs[s0 + i];
        stage[i] = rr;
        const int key = ((int)((rr >> 17) & (RB - 1)) << 3) |
                        (int)(((unsigned)rr & 0x1FFFF) >> 14);
        atomicAdd(&cnt[key], 1);
    }
    __syncthreads();

    int v[4], pre[4], sum = 0;
    const int base = t * 4;
    #pragma unroll
    for (int k = 0; k < 4; ++k) { v[k] = cnt[base + k]; pre[k] = sum; sum += v[k]; }
    s[t] = sum;
    for (int off = 1; off < 256; off <<= 1) {
        __syncthreads();
        const int w = (t >= off) ? s[t - off] : 0;
        __syncthreads();
        s[t] += w;
    }
    const int texcl = s[t] - sum;
    __syncthreads();
    #pragma unroll
    for (int k = 0; k < 4; ++k) cnt[base + k] = texcl + pre[k];
    __syncthreads();

    if (t <= RB) {
        const int r = b * RB + t;
        if (r <= n_nodes)
            offsets_row[r] = s0 + ((t == RB) ? len : cnt[t << 3]);
    }
    __syncthreads();

    for (int i = t; i < len; i += 256) {
        const ull rr = stage[i];
        const int key = ((int)((rr >> 17) & (RB - 1)) << 3) |
                        (int)(((unsigned)rr & 0x1FFFF) >> 14);
        const int p = atomicAdd(&cnt[key], 1);
        recs[s0 + p] = rr;
    }
}

// ---------------- P0: x -> fp16 (r6-verified) --------------------------------------
__global__ void tohalf_kernel(const float* __restrict__ x,
                              __half2* __restrict__ xh2, int n4)
{
    for (int i = blockIdx.x * blockDim.x + threadIdx.x; i < n4;
         i += gridDim.x * blockDim.x) {
        const float4 v = ((const float4*)x)[i];
        xh2[2 * i + 0] = __floats2half2_rn(v.x, v.y);
        xh2[2 * i + 1] = __floats2half2_rn(v.z, v.w);
    }
}

// ---------------- K6h2: CSR SpMM, split-wave half2 gathers (r3/r6 verified 84us) ---
__global__ __launch_bounds__(256, 8) void spmm_csr_half2_kernel(
    const __half* __restrict__ xh,
    const int*   __restrict__ offsets_row,
    const int*   __restrict__ binbase,
    const ull*   __restrict__ recs,
    const int*   __restrict__ flags,
    float*       __restrict__ out,
    int n_nodes)
{
    const int row  = blockIdx.x * 4 + (threadIdx.x >> 6);
    if (row >= n_nodes) return;
    const int lane = threadIdx.x & 63;
    const int b    = row >> 7;

    if (__builtin_expect(flags[b], 0)) {
        float acc = 0.f;
        const int s  = binbase[b];
        const int e  = binbase[b + 1];
        const int lr = row & (RB - 1);
        for (int j = s; j < e; ++j) {
            const ull rec = recs[j];
            if ((int)((rec >> 17) & (RB - 1)) == lr) {
                const int   c = (int)((unsigned)rec & 0x1FFFF);
                const float v = __uint_as_float((unsigned)(rec >> 32));
                acc += v * __half2float(xh[(size_t)c * D + lane]);
            }
        }
        out[(size_t)row * D + lane] = acc;
        return;
    }

    const __half2* xh2 = (const __half2*)xh;
    const int half = lane >> 5;
    const int fl   = lane & 31;

    const int s = offsets_row[row];
    const int e = offsets_row[row + 1];
    float accx = 0.f, accy = 0.f;

    int j = s;
    for (; j + 16 <= e; j += 16) {
        float vv[8]; int aa[8];
        #pragma unroll
        for (int k = 0; k < 8; ++k) {
            const ull rec = recs[j + 2 * k + half];
            vv[k] = __uint_as_float((unsigned)(rec >> 32));
            aa[k] = ((int)((unsigned)rec & 0x1FFFF) << 5) + fl;
        }
        __half2 hv[8];
        #pragma unroll
        for (int k = 0; k < 8; ++k) hv[k] = xh2[aa[k]];
        __builtin_amdgcn_sched_barrier(0);
        #pragma unroll
        for (int k = 0; k < 8; ++k) {
            const float2 xf = __half22float2(hv[k]);
            accx = fmaf(vv[k], xf.x, accx);
            accy = fmaf(vv[k], xf.y, accy);
        }
    }
    if (j < e) {
        const int safe = e - 1;
        float vv[8]; int aa[8];
        #pragma unroll
        for (int k = 0; k < 8; ++k) {
            const int  idx = j + 2 * k + half;
            const bool ok  = idx < e;
            const ull  rec = recs[ok ? idx : safe];
            vv[k] = ok ? __uint_as_float((unsigned)(rec >> 32)) : 0.f;
            aa[k] = ((int)((unsigned)rec & 0x1FFFF) << 5) + fl;
        }
        __half2 hv[8];
        #pragma unroll
        for (int k = 0; k < 8; ++k) hv[k] = xh2[aa[k]];
        __builtin_amdgcn_sched_barrier(0);
        #pragma unroll
        for (int k = 0; k < 8; ++k) {
            const float2 xf = __half22float2(hv[k]);
            accx = fmaf(vv[k], xf.x, accx);
            accy = fmaf(vv[k], xf.y, accy);
        }
    }

    accx += __shfl_xor(accx, 32);
    accy += __shfl_xor(accy, 32);
    if (half == 0) {
        float2 o; o.x = accx; o.y = accy;
        ((float2*)out)[(size_t)row * 32 + fl] = o;
    }
}

static inline size_t align16(size_t v) { return (v + 15) & ~(size_t)15; }

extern "C" void kernel_launch(void* const* d_in, const int* in_sizes, int n_in,
                              void* d_out, int out_size, void* d_ws, size_t ws_size,
                              hipStream_t stream)
{
    // setup_inputs order: t, x, edge_row, edge_col, edge_val
    const float* x        = (const float*)d_in[1];
    const int*   edge_row = (const int*)d_in[2];
    const int*   edge_col = (const int*)d_in[3];
    const float* edge_val = (const float*)d_in[4];
    float*       out      = (float*)d_out;

    const int n_edges = in_sizes[2];
    const int n_nodes = out_size / D;
    const int nb      = (n_nodes + RB - 1) / RB;
    const int chunk   = (((n_edges + NBLK1 - 1) / NBLK1) + 3) & ~3;  // x4 for int4

    // workspace carve
    const size_t off_recs    = 0;                                               // n_edges*8
    const size_t off_xh      = align16(off_recs + (size_t)n_edges * 8);         // n_nodes*128
    const size_t off_counts  = align16(off_xh + (size_t)n_nodes * D * 2);       // nb*NBLK1 u16
    const size_t off_dest    = align16(off_counts + (size_t)nb * NBLK1 * 2);    // nb*NBLK1 int
    const size_t off_binsum  = align16(off_dest + (size_t)nb * NBLK1 * 4);      // nb ints
    const size_t off_binbase = align16(off_binsum + (size_t)nb * 4);            // nb+1 ints
    const size_t off_rowoffs = align16(off_binbase + (size_t)(nb + 1) * 4);     // n_nodes+1 ints
    const size_t off_flags   = align16(off_rowoffs + (size_t)(n_nodes + 1) * 4);// nb ints
    const size_t ws_needed   = off_flags + (size_t)nb * 4;

    if (ws_size < ws_needed || nb > NB_MAX || n_nodes > (1 << 17) ||
        chunk > P1CAP || n_edges < 1) {
        hipMemsetAsync(out, 0, (size_t)out_size * sizeof(float), stream);
        const int n_blocks = (n_edges + 3) / 4;
        spmm_atomic_kernel<<<n_blocks, 256, 0, stream>>>(
            x, edge_row, edge_col, edge_val, out, n_edges);
        return;
    }

    char* ws = (char*)d_ws;
    ull*     recs        = (ull*)(ws + off_recs);
    __half*  xh          = (__half*)(ws + off_xh);
    __half2* xh2         = (__half2*)xh;
    u16*     counts      = (u16*)(ws + off_counts);
    int*     dest32      = (int*)(ws + off_dest);
    int*     binsum      = (int*)(ws + off_binsum);
    int*     binbase     = (int*)(ws + off_binbase);
    int*     offsets_row = (int*)(ws + off_rowoffs);
    int*     flags       = (int*)(ws + off_flags);

    const int n4 = (n_nodes * D) / 4;

    // preprocessing (r6 structure, r10 occupancy bump: NBLK1=1024)
    p1a_hist_kernel<<<NBLK1, 256, 0, stream>>>(
        edge_row, counts, n_edges, nb, chunk);
    p2_scanblocks_kernel<<<nb, 256, 0, stream>>>(counts, dest32, binsum, nb);
    p3_scanbins_kernel<<<1, 1024, 0, stream>>>(binsum, binbase, flags, nb);
    p1b_sortwrite_kernel<<<NBLK1, 256, 0, stream>>>(
        edge_row, edge_col, edge_val, counts, dest32, binbase,
        recs, n_edges, nb, chunk);
    p4_sortbin_kernel<<<nb, 256, 0, stream>>>(
        binbase, recs, offsets_row, flags, n_nodes);
    tohalf_kernel<<<2048, 256, 0, stream>>>(x, xh2, n4);

    // K6h2: single launch (r3/r6 verified; r9's 3-way split cost 13us, reverted)
    spmm_csr_half2_kernel<<<(n_nodes + 3) / 4, 256, 0, stream>>>(
        xh, offsets_row, binbase, recs, flags, out, n_nodes);
}